// Round 14
// baseline (75.543 us; speedup 1.0000x reference)
//
#include <hip/hip_runtime.h>
#include <hip/hip_bf16.h>
#include <stdint.h>

// Problem constants
constexpr int NA   = 10000;  // atoms
constexpr int NH   = 75;     // hidden
constexpr int NPF  = 14;     // pair features
constexpr int NW   = 5625;   // 75*75
constexpr int NCOL = 1200;   // 75*16: per h -> f=0..13 W-cols, f=14 bias, f=15 pad
constexpr int KP   = 104;    // LDS row stride (75 data, zero to 96 for 3 k-steps)
constexpr int MROW = 10112;  // NA padded to 79*128
constexpr int BN   = 240;    // gemm col-tile (15 n-frags), NCOL/BN = 5
constexpr int NGB  = (NCOL / BN) * (MROW / 128);   // 395 gemm blocks
constexpr int JSL  = 38;     // h-slots per atom in k_edges (thread does h=j, j+38)

typedef _Float16 f16;
typedef __attribute__((ext_vector_type(2))) _Float16 f16x2;
typedef __attribute__((ext_vector_type(8))) _Float16 f16x8;
typedef __attribute__((ext_vector_type(4))) float floatx4;

__device__ __forceinline__ ushort f2h_bits(float f) {
    return __builtin_bit_cast(ushort, (f16)f);       // v_cvt_f16_f32, RNE
}
__device__ __forceinline__ f16x2 bch(uint32_t w) {
    return __builtin_bit_cast(f16x2, w);
}

// bijective XCD chunk swizzle (m204)
__device__ __forceinline__ int xcd_swz(int orig, int nwg) {
    int q = nwg >> 3, r = nwg & 7;
    int xcd = orig & 7, i = orig >> 3;
    return (xcd < r ? xcd * (q + 1) : r * (q + 1) + (xcd - r) * q) + i;
}

// 16-wide f16 dot via 8x v_dot2_f32_f16 (f32 accumulate)
__device__ __forceinline__ float dot16(uint4 p0, uint4 p1, uint4 u0, uint4 u1, float c) {
    c = __builtin_amdgcn_fdot2(bch(p0.x), bch(u0.x), c, false);
    c = __builtin_amdgcn_fdot2(bch(p0.y), bch(u0.y), c, false);
    c = __builtin_amdgcn_fdot2(bch(p0.z), bch(u0.z), c, false);
    c = __builtin_amdgcn_fdot2(bch(p0.w), bch(u0.w), c, false);
    c = __builtin_amdgcn_fdot2(bch(p1.x), bch(u1.x), c, false);
    c = __builtin_amdgcn_fdot2(bch(p1.y), bch(u1.y), c, false);
    c = __builtin_amdgcn_fdot2(bch(p1.z), bch(u1.z), c, false);
    c = __builtin_amdgcn_fdot2(bch(p1.w), bch(u1.w), c, false);
    return c;
}

// ---------- K1: self-converting MFMA GEMM | pfh convert | rowstart ----------
// blocks 0..NGB-1: U[a][c] = sum_k af[a][k]*Wcol(c)[k], f32->f16 converted
// in-kernel (reg-staged to LDS); blocks NGB..NGB+bP-1: pf -> pfh f16x16;
// blocks NGB+bP..: rowstart CSR. pfh/rs are consumed only by K2.
__global__ __launch_bounds__(256, 2) void k_main(
    const float* __restrict__ af, const float* __restrict__ W,
    const float* __restrict__ bias, const float* __restrict__ pf,
    const int* __restrict__ atp,
    ushort* __restrict__ U, ushort* __restrict__ pfh, int* __restrict__ rs,
    int E, int bP)
{
    __shared__ __align__(16) ushort sm[38400];         // 26624B A + 49920B B
    const int b = blockIdx.x, tid = threadIdx.x;

    if (b < NGB) {
        ushort* As = sm;                               // [128][104]
        ushort* Bs = sm + 13312;                       // [240][104]

        const int swz = xcd_swz(b, NGB);
        const int by  = swz / (NCOL / BN);
        const int bx  = swz - by * (NCOL / BN);
        const int lane = tid & 63, wid = tid >> 6;
        const int a0 = by * 128;
        const int c0 = bx * BN;

        // Stage A: af f32 -> LDS f16 [128][104] (coalesced along k)
        for (int i = tid; i < 128 * KP; i += 256) {
            int row = i / KP, k = i - row * KP;
            int ga = a0 + row;
            float v = 0.f;
            if (k < NH && ga < NA) v = af[ga * NH + k];
            As[i] = f2h_bits(v);
        }
        // Stage B: W/bias f32 -> LDS f16 [240][104] (coalesced along k)
        for (int i = tid; i < BN * KP; i += 256) {
            int c = i / KP, k = i - c * KP;
            int gc = c0 + c;
            int h = gc >> 4, f = gc & 15;
            float v = 0.f;
            if (k < NH) {
                if (f < NPF)       v = W[f * NW + h * NH + k];
                else if (f == NPF) v = bias[h * NH + k];
            }
            Bs[i] = f2h_bits(v);
        }
        __syncthreads();

        const int lr = lane & 15;          // frag row; D col
        const int lk = (lane >> 4) * 8;    // frag k-base
        floatx4 acc[15][2] = {};

        #pragma unroll
        for (int ks = 0; ks < 3; ++ks) {
            f16x8 a[2], bv[15];
            #pragma unroll
            for (int mf = 0; mf < 2; ++mf)
                a[mf] = *(const f16x8*)&As[(wid * 32 + mf * 16 + lr) * KP + ks * 32 + lk];
            #pragma unroll
            for (int nf = 0; nf < 15; ++nf)
                bv[nf] = *(const f16x8*)&Bs[(nf * 16 + lr) * KP + ks * 32 + lk];
            #pragma unroll
            for (int nf = 0; nf < 15; ++nf)
                #pragma unroll
                for (int mf = 0; mf < 2; ++mf)
                    acc[nf][mf] = __builtin_amdgcn_mfma_f32_16x16x32_f16(
                        bv[nf], a[mf], acc[nf][mf], 0, 0, 0);
        }

        // D: col=lane&15 -> a-row; reg-axis -> 4 consecutive c
        #pragma unroll
        for (int mf = 0; mf < 2; ++mf) {
            int arow = a0 + wid * 32 + mf * 16 + lr;
            if (arow >= NA) continue;
            #pragma unroll
            for (int nf = 0; nf < 15; ++nf) {
                int cbase = c0 + nf * 16 + (lane >> 4) * 4;
                uint2 st;
                st.x = __builtin_bit_cast(uint32_t,
                         __builtin_amdgcn_cvt_pkrtz(acc[nf][mf][0], acc[nf][mf][1]));
                st.y = __builtin_bit_cast(uint32_t,
                         __builtin_amdgcn_cvt_pkrtz(acc[nf][mf][2], acc[nf][mf][3]));
                *(uint2*)&U[(size_t)arow * NCOL + cbase] = st;
            }
        }
    } else if (b < NGB + bP) {
        // pf -> f16x16 per edge, slot14 = 1.0 (bias), slot15 = 0
        int e = (b - NGB) * 256 + tid;
        if (e >= E) return;
        const float* pfe = pf + (size_t)e * NPF;
        union { f16 h[16]; uint4 q[2]; } u;
        #pragma unroll
        for (int f = 0; f < 7; ++f) {
            float2 t = *(const float2*)&pfe[2 * f];
            u.h[2 * f]     = (f16)t.x;
            u.h[2 * f + 1] = (f16)t.y;
        }
        u.h[14] = (f16)1.0f;
        u.h[15] = (f16)0.0f;
        uint4* dst = (uint4*)(pfh + (size_t)e * 16);
        dst[0] = u.q[0]; dst[1] = u.q[1];
    } else {
        // rowstart CSR from sorted atom_to_pair[:,0]
        int e = (b - NGB - bP) * 256 + tid;
        if (e >= E) return;
        int c  = atp[2 * e];
        int cp = (e == 0) ? -1 : atp[2 * (e - 1)];
        for (int a = cp + 1; a <= c; ++a) rs[a] = e;
        if (e == E - 1)
            for (int a = c + 1; a <= NA; ++a) rs[a] = E;
    }
}

// ---------- K2: per-(atom, j) edge loop; thread handles h=j and h=j+38 ----------
// (r6-identical) XCD chunk swizzle: each XCD owns a contiguous atom range whose
// U band (~3 MB) fits its 4 MiB L2 (both index columns are sorted).
__global__ __launch_bounds__(256) void k_edges2(
    const ushort* __restrict__ pfh, const int* __restrict__ atp,
    const int* __restrict__ rs, const ushort* __restrict__ U,
    float* __restrict__ out, int nwg)
{
    int blk = xcd_swz(blockIdx.x, nwg);
    int idx = blk * 256 + threadIdx.x;
    if (idx >= NA * JSL) return;
    int a = idx / JSL;
    int j = idx - a * JSL;
    const bool two = (j + JSL) < NH;   // j < 37
    int e0 = rs[a], e1 = rs[a + 1];

    float acc0 = 0.f, acc1 = 0.f;
    for (int e = e0; e < e1; ++e) {
        int a1 = atp[2 * e + 1];
        const uint4* pq = (const uint4*)(pfh + (size_t)e * 16);
        uint4 p0 = pq[0], p1 = pq[1];
        const ushort* ub = U + (size_t)a1 * NCOL;
        {
            const uint4* up = (const uint4*)(ub + j * 16);
            acc0 = dot16(p0, p1, up[0], up[1], acc0);
        }
        if (two) {
            const uint4* up = (const uint4*)(ub + (j + JSL) * 16);
            acc1 = dot16(p0, p1, up[0], up[1], acc1);
        }
    }
    out[a * NH + j] = acc0;
    if (two) out[a * NH + j + JSL] = acc1;
}

// ---------- Fallback: direct per-(edge,h) with atomics (fp32) ----------
__global__ void k_naive(const float* __restrict__ pf, const float* __restrict__ af,
                        const int* __restrict__ atp, const float* __restrict__ W,
                        const float* __restrict__ bias, float* __restrict__ out, int E)
{
    int idx = blockIdx.x * blockDim.x + threadIdx.x;
    if (idx >= E * NH) return;
    int e = idx / NH, h = idx - e * NH;
    int a0 = atp[2 * e], a1 = atp[2 * e + 1];
    float p[NPF];
    #pragma unroll
    for (int f = 0; f < NPF; ++f) p[f] = pf[(size_t)e * NPF + f];
    float acc = 0.f;
    for (int k = 0; k < NH; ++k) {
        float w = bias[h * NH + k];
        #pragma unroll
        for (int f = 0; f < NPF; ++f) w += p[f] * W[f * NW + h * NH + k];
        acc += w * af[a1 * NH + k];
    }
    atomicAdd(&out[a0 * NH + h], acc);
}

extern "C" void kernel_launch(void* const* d_in, const int* in_sizes, int n_in,
                              void* d_out, int out_size, void* d_ws, size_t ws_size,
                              hipStream_t stream) {
    const float* pf   = (const float*)d_in[0];
    const float* af   = (const float*)d_in[1];
    const int*   atp  = (const int*)d_in[2];
    const float* W    = (const float*)d_in[3];
    const float* bias = (const float*)d_in[4];
    float* out = (float*)d_out;
    const int E = in_sizes[2] / 2;

    const size_t offU   = 0;
    const size_t offPfh = offU + (size_t)NA * NCOL * 2;        // 24,000,000
    const size_t offRs  = offPfh + (size_t)E * 16 * 2;         // +2,048,000
    const size_t need   = offRs + (size_t)(NA + 1) * sizeof(int);

    if (ws_size >= need) {
        ushort* U   = (ushort*)((char*)d_ws + offU);
        ushort* pfh = (ushort*)((char*)d_ws + offPfh);
        int*    rs  = (int*)((char*)d_ws + offRs);

        const int bP = (E + 255) / 256;                 // 250
        const int bR = (E + 255) / 256;                 // 250
        k_main<<<NGB + bP + bR, 256, 0, stream>>>(af, W, bias, pf, atp,
                                                  U, pfh, rs, E, bP);

        const int nwg2 = (NA * JSL + 255) / 256;        // 1485
        k_edges2<<<nwg2, 256, 0, stream>>>(pfh, atp, rs, U, out, nwg2);
    } else {
        hipMemsetAsync(d_out, 0, (size_t)out_size * sizeof(float), stream);
        k_naive<<<((size_t)E * NH + 255) / 256, 256, 0, stream>>>(pf, af, atp, W, bias, out, E);
    }
}